// Round 9
// baseline (283.111 us; speedup 1.0000x reference)
//
#include <hip/hip_runtime.h>

#define B_ 8
#define N_ 2048
#define FIN_ 512
#define FOUT_ 512

typedef __attribute__((ext_vector_type(8))) short short8;
typedef __attribute__((ext_vector_type(4))) float floatx4;
typedef __attribute__((ext_vector_type(4))) unsigned short ushortx4;
typedef __attribute__((ext_vector_type(8))) unsigned short ushortx8;

__device__ inline unsigned short f2bf(float f) {
    union { float f; unsigned int u; } x; x.f = f;
    unsigned int r = x.u + 0x7FFFu + ((x.u >> 16) & 1u);  // RNE
    return (unsigned short)(r >> 16);
}

__device__ inline void glds16(const void* g, void* l) {
    __builtin_amdgcn_global_load_lds(
        (const __attribute__((address_space(1))) void*)g,
        (__attribute__((address_space(3))) void*)l, 16, 0, 0);
}

// --- 1) FUSED PREP v2 --------------------------------------------------------
// Grid 4096 x 256.  WAVE-PER-ROW degree+cast: each wave owns one A row
// (lane l: 8 independent float4 loads at chunk c*64+l -> 8-deep MLP, lane-
// local sum, ONE shuffle chain, no LDS / no __syncthreads on this path).
// Every block also casts one 2048-elem X chunk; blocks <256 transpose W.
__global__ __launch_bounds__(256) void prep_kernel(
    const float* __restrict__ A, float* __restrict__ dinv,
    unsigned short* __restrict__ Abf,
    const float* __restrict__ X, unsigned short* __restrict__ Xbf,
    const float* __restrict__ W, unsigned short* __restrict__ Wt) {
    int t = threadIdx.x;
    int bid = blockIdx.x;             // 0..4095

    // ---- X cast (every block, one 2048-elem chunk) ----
    {
        size_t e0 = ((size_t)bid * 256 + t) * 8;
        float4 a0 = *(const float4*)(X + e0);
        float4 a1 = *(const float4*)(X + e0 + 4);
        float av[8] = {a0.x, a0.y, a0.z, a0.w, a1.x, a1.y, a1.z, a1.w};
        ushortx8 p;
#pragma unroll
        for (int r = 0; r < 8; ++r) p[r] = f2bf(av[r]);
        *(ushortx8*)(Xbf + e0) = p;
    }

    // ---- W transpose (blocks 0..255) ----
    __shared__ float tile[32][33];
    if (bid < 256) {
        int bx = (bid & 15) * 32;   // F_OUT block
        int by = (bid >> 4) * 32;   // F_IN block
        int tx = t & 31, ty = t >> 5;   // 32 x 8
#pragma unroll
        for (int r = 0; r < 32; r += 8)
            tile[ty + r][tx] = W[(size_t)(by + ty + r) * FOUT_ + bx + tx];
        __syncthreads();
#pragma unroll
        for (int r = 0; r < 32; r += 8)
            Wt[(size_t)(bx + ty + r) * FIN_ + by + tx] = f2bf(tile[tx][ty + r]);
    }

    // ---- degree + A cast: wave-per-row, 8-deep MLP ----
    int lane = t & 63;
    int row = bid * 4 + (t >> 6);     // 4 waves -> 4 rows; 4096*4 = 16384 rows
    size_t base = (size_t)row * N_;
    const float4* A4 = (const float4*)(A + base);
    float4 v[8];
#pragma unroll
    for (int c = 0; c < 8; ++c) v[c] = A4[c * 64 + lane];   // 8 loads in flight
    float s = 0.f;
#pragma unroll
    for (int c = 0; c < 8; ++c) {
        ushortx4 p;
        p[0] = f2bf(v[c].x); p[1] = f2bf(v[c].y);
        p[2] = f2bf(v[c].z); p[3] = f2bf(v[c].w);
        *(ushortx4*)(Abf + base + (size_t)(c * 64 + lane) * 4) = p;
        s += v[c].x + v[c].y + v[c].z + v[c].w;
    }
#pragma unroll
    for (int off = 32; off > 0; off >>= 1) s += __shfl_down(s, off, 64);
    if (lane == 0) dinv[row] = rsqrtf(s + 1.0f);
}

// ============================================================================
// Swizzled LDS tile: rows of BK=64 bf16 (128 B = 8 chunks of 16 B).
// chunk' = chunk ^ (row & 7).  Staging thread t of issue u lands at flat byte
// u*4096 + t*16 -> row = u*32 + (t>>3), chunk' = t&7, so it fetches global
// chunk c = (t&7) ^ ((t>>3)&7).  SQ_LDS_BANK_CONFLICT = 0 (verified).
//
// Phased 2-deep pipeline (T3+T4+T5) — best measured structure (round 3).
// ============================================================================

// --- 2) GEMM1: y^T = ((Xbf @ Wt^T + b) * d_node)^T, 128x128 tile, BK=64 -----
__global__ __launch_bounds__(256) void gemm1_kernel(
    const unsigned short* __restrict__ Abase,   // Xbf [16384][512]
    const unsigned short* __restrict__ Btbase,  // Wt  [512][512]
    unsigned short* __restrict__ XwT,           // [8][512][2048]  (= y^T)
    const float* __restrict__ bias,
    const float* __restrict__ dinv) {           // [16384]
    __shared__ __align__(16) char smem[65536];  // 2 x (As 16KB + Bs 16KB); epi reuses

    int t = threadIdx.x;
    int lane = t & 63;
    int wave = t >> 6;
    int wr = wave >> 1, wc = wave & 1;
    int q = lane >> 4, m = lane & 15;
    int n0 = blockIdx.x * 128;   // FOUT block
    int m0 = blockIdx.y * 128;   // node block (flat b*N+node)

    int srow = t >> 3;                       // 0..31 per issue
    int scol = (((t & 7) ^ (srow & 7)) * 8); // global elem chunk start
    int x0 = ((q ^ (m & 7)) * 16);           // sub-slab 0 chunk byte
    int x1 = x0 ^ 64;                        // sub-slab 1

    floatx4 acc[4][4];
#pragma unroll
    for (int mi = 0; mi < 4; ++mi)
#pragma unroll
        for (int ni = 0; ni < 4; ++ni)
            acc[mi][ni] = (floatx4){0.f, 0.f, 0.f, 0.f};

    const unsigned short* gA = Abase + (size_t)(m0 + srow) * FIN_ + scol;
    const unsigned short* gB = Btbase + (size_t)(n0 + srow) * FIN_ + scol;

#define STAGE1(bufi) do {                                              \
        char* lA = smem + (bufi) * 32768 + wave * 1024;                \
        char* lB = smem + (bufi) * 32768 + 16384 + wave * 1024;        \
        _Pragma("unroll")                                              \
        for (int u = 0; u < 4; ++u) {                                  \
            glds16(gA + (size_t)(u * 32) * FIN_, lA + u * 4096);       \
            glds16(gB + (size_t)(u * 32) * FIN_, lB + u * 4096);       \
        }                                                              \
        gA += 64; gB += 64;                                            \
    } while (0)

    STAGE1(0);
    STAGE1(1);

    const int NT = FIN_ / 64;   // 8
    for (int kt = 0; kt < NT; ++kt) {
        if (kt < NT - 1) asm volatile("s_waitcnt vmcnt(8)" ::: "memory");
        else             asm volatile("s_waitcnt vmcnt(0)" ::: "memory");
        __builtin_amdgcn_sched_barrier(0);
        __builtin_amdgcn_s_barrier();                   // tile kt resident
        const char* As = smem + (kt & 1) * 32768;
        const char* Bs = As + 16384;
        short8 af0[4], bf0[4], af1[4], bf1[4];
#pragma unroll
        for (int mi = 0; mi < 4; ++mi)
            af0[mi] = *(const short8*)(As + (wr * 64 + mi * 16 + m) * 128 + x0);
#pragma unroll
        for (int ni = 0; ni < 4; ++ni)
            bf0[ni] = *(const short8*)(Bs + (wc * 64 + ni * 16 + m) * 128 + x0);
#pragma unroll
        for (int mi = 0; mi < 4; ++mi)
            af1[mi] = *(const short8*)(As + (wr * 64 + mi * 16 + m) * 128 + x1);
#pragma unroll
        for (int ni = 0; ni < 4; ++ni)
            bf1[ni] = *(const short8*)(Bs + (wc * 64 + ni * 16 + m) * 128 + x1);
        asm volatile("s_waitcnt lgkmcnt(8)" ::: "memory");  // sl0 frags landed
        __builtin_amdgcn_sched_barrier(0);
        __builtin_amdgcn_s_setprio(1);
#pragma unroll
        for (int mi = 0; mi < 4; ++mi)
#pragma unroll
            for (int ni = 0; ni < 4; ++ni)
                acc[mi][ni] = __builtin_amdgcn_mfma_f32_16x16x32_bf16(
                    af0[mi], bf0[ni], acc[mi][ni], 0, 0, 0);
        __builtin_amdgcn_s_setprio(0);
        asm volatile("s_waitcnt lgkmcnt(0)" ::: "memory");  // sl1 landed too
        __builtin_amdgcn_sched_barrier(0);
        __builtin_amdgcn_s_barrier();                   // all waves pulled kt
        if (kt + 2 < NT) STAGE1(kt & 1);                // overwrite consumed buf
        __builtin_amdgcn_sched_barrier(0);
        __builtin_amdgcn_s_setprio(1);
#pragma unroll
        for (int mi = 0; mi < 4; ++mi)
#pragma unroll
            for (int ni = 0; ni < 4; ++ni)
                acc[mi][ni] = __builtin_amdgcn_mfma_f32_16x16x32_bf16(
                    af1[mi], bf1[ni], acc[mi][ni], 0, 0, 0);
        __builtin_amdgcn_s_setprio(0);
    }
#undef STAGE1

    // ---- epilogue: (acc + bias) * dinv_node, transpose via LDS, store ------
    unsigned short* T = (unsigned short*)smem;  // [128][136]
#pragma unroll
    for (int mi = 0; mi < 4; ++mi) {
        int row = wr * 64 + mi * 16 + q * 4;       // node-local (4 consecutive)
        float4 dv = *(const float4*)(dinv + m0 + row);
        float dr[4] = {dv.x, dv.y, dv.z, dv.w};
#pragma unroll
        for (int ni = 0; ni < 4; ++ni) {
            int col = wc * 64 + ni * 16 + m;       // f-local
            float bv = bias[n0 + col];
            ushortx4 pk;
#pragma unroll
            for (int r = 0; r < 4; ++r) pk[r] = f2bf((acc[mi][ni][r] + bv) * dr[r]);
            *(ushortx4*)(T + col * 136 + row) = pk;
        }
    }
    __syncthreads();
    int f  = t >> 1;             // 0..127
    int c0 = (t & 1) * 64;       // node half
    int bb = m0 >> 11;
    int node0 = (m0 & 2047) + c0;
    unsigned short* dst = XwT + ((size_t)bb * FOUT_ + n0 + f) * N_ + node0;
    const unsigned short* src = T + f * 136 + c0;
#pragma unroll
    for (int u = 0; u < 8; ++u)
        *(ushortx8*)(dst + u * 8) = *(const ushortx8*)(src + u * 8);
}

// --- 3) GEMM2: out[b,i,:] = d_i * (Abf[b,i,:] @ y[b] + y[b,i,:]) ------------
// 128x128 tile, BK=64, swizzled LDS, XCD-aware 1D grid (batch = id & 7),
// phased 2-deep counted-vmcnt pipeline (best measured, round 3).
__global__ __launch_bounds__(256) void gemm2_kernel(
    const unsigned short* __restrict__ Abf,   // [8][2048][2048] raw bf16(A)
    const unsigned short* __restrict__ XwT,   // [8][512][2048]  (= y^T = B^T)
    const float* __restrict__ dinv,           // [16384]
    float* __restrict__ out) {                // [8][2048][512]
    __shared__ __align__(16) char smem[65536];  // 2 x (As 16KB + Bs 16KB)

    int t = threadIdx.x;
    int lane = t & 63;
    int wave = t >> 6;
    int wr = wave >> 1, wc = wave & 1;
    int q = lane >> 4, m = lane & 15;

    int id = blockIdx.x;
    int b  = id & 7;             // XCD pin
    int s  = id >> 3;            // 0..63 within batch
    int n0 = (s & 3) * 128;      // n-siblings adjacent in time
    int m0 = (s >> 2) * 128;

    const unsigned short* Ab = Abf + (size_t)b * N_ * N_;
    const unsigned short* Bb = XwT + (size_t)b * FOUT_ * N_;

    int srow = t >> 3;
    int scol = (((t & 7) ^ (srow & 7)) * 8);
    int x0 = ((q ^ (m & 7)) * 16);
    int x1 = x0 ^ 64;

    floatx4 acc[4][4];
#pragma unroll
    for (int mi = 0; mi < 4; ++mi)
#pragma unroll
        for (int ni = 0; ni < 4; ++ni)
            acc[mi][ni] = (floatx4){0.f, 0.f, 0.f, 0.f};

    const unsigned short* gA = Ab + (size_t)(m0 + srow) * N_ + scol;
    const unsigned short* gB = Bb + (size_t)(n0 + srow) * N_ + scol;

#define STAGE2(bufi) do {                                              \
        char* lA = smem + (bufi) * 32768 + wave * 1024;                \
        char* lB = smem + (bufi) * 32768 + 16384 + wave * 1024;        \
        _Pragma("unroll")                                              \
        for (int u = 0; u < 4; ++u) {                                  \
            glds16(gA + (size_t)(u * 32) * N_, lA + u * 4096);         \
            glds16(gB + (size_t)(u * 32) * N_, lB + u * 4096);         \
        }                                                              \
        gA += 64; gB += 64;                                            \
    } while (0)

    STAGE2(0);
    STAGE2(1);

    const int NT = N_ / 64;   // 32
    for (int kt = 0; kt < NT; ++kt) {
        if (kt < NT - 1) asm volatile("s_waitcnt vmcnt(8)" ::: "memory");
        else             asm volatile("s_waitcnt vmcnt(0)" ::: "memory");
        __builtin_amdgcn_sched_barrier(0);
        __builtin_amdgcn_s_barrier();                   // tile kt resident
        const char* As = smem + (kt & 1) * 32768;
        const char* Bs = As + 16384;
        short8 af0[4], bf0[4], af1[4], bf1[4];
#pragma unroll
        for (int mi = 0; mi < 4; ++mi)
            af0[mi] = *(const short8*)(As + (wr * 64 + mi * 16 + m) * 128 + x0);
#pragma unroll
        for (int ni = 0; ni < 4; ++ni)
            bf0[ni] = *(const short8*)(Bs + (wc * 64 + ni * 16 + m) * 128 + x0);
#pragma unroll
        for (int mi = 0; mi < 4; ++mi)
            af1[mi] = *(const short8*)(As + (wr * 64 + mi * 16 + m) * 128 + x1);
#pragma unroll
        for (int ni = 0; ni < 4; ++ni)
            bf1[ni] = *(const short8*)(Bs + (wc * 64 + ni * 16 + m) * 128 + x1);
        asm volatile("s_waitcnt lgkmcnt(8)" ::: "memory");  // sl0 frags landed
        __builtin_amdgcn_sched_barrier(0);
        __builtin_amdgcn_s_setprio(1);
#pragma unroll
        for (int mi = 0; mi < 4; ++mi)
#pragma unroll
            for (int ni = 0; ni < 4; ++ni)
                acc[mi][ni] = __builtin_amdgcn_mfma_f32_16x16x32_bf16(
                    af0[mi], bf0[ni], acc[mi][ni], 0, 0, 0);
        __builtin_amdgcn_s_setprio(0);
        asm volatile("s_waitcnt lgkmcnt(0)" ::: "memory");  // sl1 landed too
        __builtin_amdgcn_sched_barrier(0);
        __builtin_amdgcn_s_barrier();                   // all waves pulled kt
        if (kt + 2 < NT) STAGE2(kt & 1);                // overwrite consumed buf
        __builtin_amdgcn_sched_barrier(0);
        __builtin_amdgcn_s_setprio(1);
#pragma unroll
        for (int mi = 0; mi < 4; ++mi)
#pragma unroll
            for (int ni = 0; ni < 4; ++ni)
                acc[mi][ni] = __builtin_amdgcn_mfma_f32_16x16x32_bf16(
                    af1[mi], bf1[ni], acc[mi][ni], 0, 0, 0);
        __builtin_amdgcn_s_setprio(0);
    }
#undef STAGE2

    // C/D layout: col = lane&15, row = (lane>>4)*4 + reg
    // out_row = d_row * (acc_row + y_row[col]),  y = XwT[b][col][row] (bf16)
    float* C = out + (size_t)b * N_ * FOUT_;
#pragma unroll
    for (int mi = 0; mi < 4; ++mi) {
        int rowb = m0 + wr * 64 + mi * 16 + q * 4;
        float4 dv = *(const float4*)(dinv + b * N_ + rowb);
        float dr[4] = {dv.x, dv.y, dv.z, dv.w};
#pragma unroll
        for (int ni = 0; ni < 4; ++ni) {
            int col = n0 + wc * 64 + ni * 16 + m;
            ushortx4 yv = *(const ushortx4*)(Bb + (size_t)col * N_ + rowb);
#pragma unroll
            for (int r = 0; r < 4; ++r) {
                union { unsigned int u; float f; } yc; yc.u = ((unsigned int)yv[r]) << 16;
                C[(size_t)(rowb + r) * FOUT_ + col] = dr[r] * (acc[mi][ni][r] + yc.f);
            }
        }
    }
}

extern "C" void kernel_launch(void* const* d_in, const int* in_sizes, int n_in,
                              void* d_out, int out_size, void* d_ws, size_t ws_size,
                              hipStream_t stream) {
    const float* X    = (const float*)d_in[0];   // [8,2048,512]
    const float* A    = (const float*)d_in[1];   // [8,2048,2048]
    const float* W    = (const float*)d_in[2];   // [512,512]
    const float* bias = (const float*)d_in[3];   // [512]
    float* out = (float*)d_out;                  // [8,2048,512] fp32
    char* ws = (char*)d_ws;

    float* dinv          = (float*)(ws);                              // 64 KB
    unsigned short* Xbf  = (unsigned short*)(ws + (1u << 16));        // 16 MB
    unsigned short* Wt   = (unsigned short*)(ws + (1u << 16) + 16777216u);           // 512 KB
    unsigned short* XwT  = (unsigned short*)(ws + (1u << 16) + 16777216u + 524288u); // 16 MB
    unsigned short* Abf  = (unsigned short*)(ws + (1u << 16) + 16777216u + 524288u + 16777216u); // 64 MB

    prep_kernel<<<B_ * N_ / 4, 256, 0, stream>>>(A, dinv, Abf, X, Xbf, W, Wt);

    gemm1_kernel<<<dim3(FOUT_ / 128, (B_ * N_) / 128), 256, 0, stream>>>(
        Xbf, Wt, XwT, bias, dinv);

    gemm2_kernel<<<512, 256, 0, stream>>>(Abf, XwT, dinv, out);
}